// Round 3
// baseline (86.055 us; speedup 1.0000x reference)
//
#include <hip/hip_runtime.h>
#include <hip/hip_cooperative_groups.h>
#include <math.h>

namespace cg = cooperative_groups;

#define N 4096
#define M 4095          // number of segments
#define EPSF 1e-9f
#define NB 64           // 64 blocks x 64 threads = 1 wave/block, 4096 lanes
#define INV_4PI 0.07957747154594767f

// Algebra (verified absmax 0.0 in rounds 0-2):
//  (1) q_bio = normalize(eye(4)[idx]) is an EXACT one-hot in fp32
//      (1.0f + 1e-9f == 1.0f), so (dr2_j, m2_j) depends only on the type
//      t=(idx[j], idx[j+1]) -- compile-time constants; O(M^2) -> O(M*6).
//  (2) Swapping (a,b)->(b,a) flips dr2 but keeps m2: antisymmetric, 12
//      ordered types fold to 6 with signed weights w_ab = cnt[a,b]-cnt[b,a].
//  (3) sum_i sum_t w[t]*f_t(i) == sum_t w[t]*(sum_i f_t(i)): weights factor
//      out of the double sum; W and S accumulate independently and multiply
//      once at the very end (no histogram pre-pass, no atomics).
//  (4) theta = b/255 * 2pi and v_sin_f32/v_cos_f32 take REVOLUTIONS:
//      sin(theta) = v_sin(b/255), b/255 in [0,1) -- no range reduction.
//  (5) R2 measured: spreading across 64 CUs beat the single-CU block by
//      ~2 us. Remaining controllable cost is GRAPH NODE COUNT (~1.5-2 us
//      gap per node). NEW this round: fuse the two nodes into ONE
//      cooperative kernel; grid.sync() replaces the kernel boundary.
//      __threadfence() (device scope) on both sides of the sync handles
//      cross-XCD L2 visibility of the ws partials.

__device__ __forceinline__ void norm_point(float b, float& x, float& y, float& z) {
  float rev = b * (1.0f / 255.0f);               // revolutions in [0,1)
  float s = __builtin_amdgcn_sinf(rev);          // v_sin_f32: sin(2*pi*rev)
  float c = __builtin_amdgcn_cosf(rev);          // v_cos_f32
  float q1 = 0.5f * s, q2 = 0.3f * s, q3 = 0.2f * s;
  float n2 = c * c + q1 * q1 + q2 * q2 + q3 * q3 + EPSF;
  float inv = rsqrtf(n2);
  inv = inv * (1.5f - 0.5f * n2 * inv * inv);    // Newton -> ~1 ulp
  x = q1 * inv; y = q2 * inv; z = q3 * inv;
}

__global__ __launch_bounds__(64) void gauss_coop(
    const float* __restrict__ bytes, const int* __restrict__ idx,
    float* __restrict__ ws, float* __restrict__ out) {
  const int s = blockIdx.x * 64 + threadIdx.x;   // segment id, one per lane

  // 6 unordered types (a<b): dr2 = P[b]-P[a], m2 = (P[a]+P[b])/2, const-folded.
  const float EX[6] = {1.f, 0.f, 0.f, -1.f, -1.f, 0.f};
  const float EY[6] = {0.f, 1.f, 0.f, 1.f, 0.f, -1.f};
  const float EZ[6] = {0.f, 0.f, 1.f, 0.f, 1.f, 1.f};
  const float M2X[6] = {0.5f, 0.f, 0.f, 0.5f, 0.5f, 0.f};
  const float M2Y[6] = {0.f, 0.5f, 0.f, 0.5f, 0.f, 0.5f};
  const float M2Z[6] = {0.f, 0.f, 0.5f, 0.f, 0.5f, 0.5f};
  const int AB[6] = {0 * 4 + 1, 0 * 4 + 2, 0 * 4 + 3, 1 * 4 + 2, 1 * 4 + 3, 2 * 4 + 3};
  const int BA[6] = {1 * 4 + 0, 2 * 4 + 0, 3 * 4 + 0, 2 * 4 + 1, 3 * 4 + 1, 3 * 4 + 2};

  float S[6] = {0.f, 0.f, 0.f, 0.f, 0.f, 0.f};
  float W[6] = {0.f, 0.f, 0.f, 0.f, 0.f, 0.f};

  if (s < M) {
    float ax, ay, az, bx, by, bz;
    norm_point(bytes[s], ax, ay, az);
    norm_point(bytes[s + 1], bx, by, bz);
    const int u = idx[s] * 4 + idx[s + 1];

    const float d1x = bx - ax, d1y = by - ay, d1z = bz - az;
    const float m1x = 0.5f * (bx + ax), m1y = 0.5f * (by + ay), m1z = 0.5f * (bz + az);

#pragma unroll
    for (int q = 0; q < 6; ++q) {
      float dx = m1x - M2X[q], dy = m1y - M2Y[q], dz = m1z - M2Z[q];
      float cx = d1y * EZ[q] - d1z * EY[q];      // cross(d1, e), e in {0,+-1}
      float cy = d1z * EX[q] - d1x * EZ[q];      // -> const-folds to adds
      float cz = d1x * EY[q] - d1y * EX[q];
      float num = cx * dx + cy * dy + cz * dz;
      float d2 = dx * dx + dy * dy + dz * dz + EPSF;
      float inv = rsqrtf(d2);
      inv = inv * (1.5f - 0.5f * d2 * inv * inv);   // Newton -> ~1 ulp
      S[q] = num * (inv * inv * inv);
      W[q] = (u == AB[q] ? 1.0f : 0.0f) - (u == BA[q] ? 1.0f : 0.0f);
    }
  }

  // 64-lane wave reduction of the 12 partials (no LDS, no intra-block barrier).
#pragma unroll
  for (int off = 32; off > 0; off >>= 1) {
#pragma unroll
    for (int q = 0; q < 6; ++q) {
      S[q] += __shfl_down(S[q], off, 64);
      W[q] += __shfl_down(W[q], off, 64);
    }
  }
  if (threadIdx.x == 0) {
#pragma unroll
    for (int q = 0; q < 6; ++q) {
      ws[q * NB + blockIdx.x] = S[q];            // type-major for the finisher
      ws[(6 + q) * NB + blockIdx.x] = W[q];
    }
  }

  // ---- grid-wide sync: release our partials, wait for all 64 blocks ----
  __threadfence();                               // device-scope release (cross-XCD)
  cg::this_grid().sync();

  // ---- finisher: block 0's single wave reduces the 64x12 partials ----
  if (blockIdx.x == 0) {
    __threadfence();                             // acquire side
    const int l = threadIdx.x;                   // lane l holds block l's partials
    float v[12];
#pragma unroll
    for (int q = 0; q < 12; ++q) v[q] = ws[q * NB + l];
#pragma unroll
    for (int off = 32; off > 0; off >>= 1) {
#pragma unroll
      for (int q = 0; q < 12; ++q) v[q] += __shfl_down(v[q], off, 64);
    }
    if (l == 0) {
      float r = 0.0f;
#pragma unroll
      for (int q = 0; q < 6; ++q) r += v[6 + q] * v[q];   // sum_t w[t]*S[t]
      out[0] = r * INV_4PI;
    }
  }
}

extern "C" void kernel_launch(void* const* d_in, const int* in_sizes, int n_in,
                              void* d_out, int out_size, void* d_ws, size_t ws_size,
                              hipStream_t stream) {
  const float* bytes = (const float*)d_in[0];
  const int* idx = (const int*)d_in[1];
  float* out = (float*)d_out;
  float* ws = (float*)d_ws;

  void* args[] = {(void*)&bytes, (void*)&idx, (void*)&ws, (void*)&out};
  hipLaunchCooperativeKernel((const void*)gauss_coop, dim3(NB), dim3(64),
                             args, 0, stream);
}

// Round 4
// 56.442 us; speedup vs baseline: 1.5246x; 1.5246x over previous
//
#include <hip/hip_runtime.h>
#include <math.h>

#define N 4096
#define M 4095          // number of segments
#define EPSF 1e-9f
#define NB 64           // 64 blocks x 64 threads = 1 wave/block, 4096 lanes
#define INV_4PI 0.07957747154594767f
#define MAGIC 0x600DBEA7u   // arrival flag; avoids common poison patterns
                            // (0x00000000 / 0xFFFFFFFF / 0xCCCCCCCC /
                            //  0xDEADBEEF / 0xCAFEBABE). Collision would show
                            // as absmax failure, never a hang.

// Algebra (verified absmax 0.0 in rounds 0-3):
//  (1) q_bio = normalize(eye(4)[idx]) is an EXACT one-hot in fp32
//      (1.0f + 1e-9f == 1.0f), so (dr2_j, m2_j) depends only on the type
//      t=(idx[j], idx[j+1]) -- compile-time constants; O(M^2) -> O(M*6).
//  (2) Swapping (a,b)->(b,a) flips dr2 but keeps m2: antisymmetric, 12
//      ordered types fold to 6 with signed weights w_ab = cnt[a,b]-cnt[b,a].
//  (3) sum_i sum_t w[t]*f_t(i) == sum_t w[t]*(sum_i f_t(i)): weights factor
//      out; W and S accumulate independently, multiplied once at the end.
//  (4) theta = b/255 * 2pi and v_sin_f32/v_cos_f32 take REVOLUTIONS:
//      sin(theta) = v_sin(b/255), b/255 in [0,1) -- no range reduction.
//  (5) R2 measured: 64-CU spread beats single-CU by ~2 us (58.1 vs 60.0).
//  (6) R3 measured: hipLaunchCooperativeKernel costs +28 us under graph
//      capture -- coop dispatch is NOT a cheap graph node. REVERTED.
//  (7) NEW this round: single NON-coop node. Blocks publish partials +
//      MAGIC flag with agent-scope release; block 0 spin-waits on the 64
//      flags with agent-scope acquire (per-XCD L2s are not coherent, so
//      plain loads could hit stale poison lines), then reduces. Only
//      block 0 waits -> no deadlock regardless of residency. The per-
//      iteration ws poison fill clears stale flags from prior iterations.

__device__ __forceinline__ void norm_point(float b, float& x, float& y, float& z) {
  float rev = b * (1.0f / 255.0f);               // revolutions in [0,1)
  float s = __builtin_amdgcn_sinf(rev);          // v_sin_f32: sin(2*pi*rev)
  float c = __builtin_amdgcn_cosf(rev);          // v_cos_f32
  float q1 = 0.5f * s, q2 = 0.3f * s, q3 = 0.2f * s;
  float n2 = c * c + q1 * q1 + q2 * q2 + q3 * q3 + EPSF;
  float inv = rsqrtf(n2);
  inv = inv * (1.5f - 0.5f * n2 * inv * inv);    // Newton -> ~1 ulp
  x = q1 * inv; y = q2 * inv; z = q3 * inv;
}

__global__ __launch_bounds__(64) void gauss_fused(
    const float* __restrict__ bytes, const int* __restrict__ idx,
    float* __restrict__ ws, float* __restrict__ out) {
  const int l = threadIdx.x;
  const int b = blockIdx.x;
  const int s = b * 64 + l;                      // segment id, one per lane

  // 6 unordered types (a<b): dr2 = P[b]-P[a], m2 = (P[a]+P[b])/2, const-folded.
  const float EX[6] = {1.f, 0.f, 0.f, -1.f, -1.f, 0.f};
  const float EY[6] = {0.f, 1.f, 0.f, 1.f, 0.f, -1.f};
  const float EZ[6] = {0.f, 0.f, 1.f, 0.f, 1.f, 1.f};
  const float M2X[6] = {0.5f, 0.f, 0.f, 0.5f, 0.5f, 0.f};
  const float M2Y[6] = {0.f, 0.5f, 0.f, 0.5f, 0.f, 0.5f};
  const float M2Z[6] = {0.f, 0.f, 0.5f, 0.f, 0.5f, 0.5f};
  const int AB[6] = {0 * 4 + 1, 0 * 4 + 2, 0 * 4 + 3, 1 * 4 + 2, 1 * 4 + 3, 2 * 4 + 3};
  const int BA[6] = {1 * 4 + 0, 2 * 4 + 0, 3 * 4 + 0, 2 * 4 + 1, 3 * 4 + 1, 3 * 4 + 2};

  float S[6] = {0.f, 0.f, 0.f, 0.f, 0.f, 0.f};
  float W[6] = {0.f, 0.f, 0.f, 0.f, 0.f, 0.f};

  if (s < M) {
    float ax, ay, az, bx, by, bz;
    norm_point(bytes[s], ax, ay, az);
    norm_point(bytes[s + 1], bx, by, bz);
    const int u = idx[s] * 4 + idx[s + 1];

    const float d1x = bx - ax, d1y = by - ay, d1z = bz - az;
    const float m1x = 0.5f * (bx + ax), m1y = 0.5f * (by + ay), m1z = 0.5f * (bz + az);

#pragma unroll
    for (int q = 0; q < 6; ++q) {
      float dx = m1x - M2X[q], dy = m1y - M2Y[q], dz = m1z - M2Z[q];
      float cx = d1y * EZ[q] - d1z * EY[q];      // cross(d1, e), e in {0,+-1}
      float cy = d1z * EX[q] - d1x * EZ[q];      // -> const-folds to adds
      float cz = d1x * EY[q] - d1y * EX[q];
      float num = cx * dx + cy * dy + cz * dz;
      float d2 = dx * dx + dy * dy + dz * dz + EPSF;
      float inv = rsqrtf(d2);
      inv = inv * (1.5f - 0.5f * d2 * inv * inv);   // Newton -> ~1 ulp
      S[q] = num * (inv * inv * inv);
      W[q] = (u == AB[q] ? 1.0f : 0.0f) - (u == BA[q] ? 1.0f : 0.0f);
    }
  }

  // 64-lane wave reduction of the 12 partials (no LDS, no barrier).
#pragma unroll
  for (int off = 32; off > 0; off >>= 1) {
#pragma unroll
    for (int q = 0; q < 6; ++q) {
      S[q] += __shfl_down(S[q], off, 64);
      W[q] += __shfl_down(W[q], off, 64);
    }
  }

  unsigned int* flags = (unsigned int*)(ws + 12 * NB);
  if (l == 0) {
    // Publish partials (agent scope so they reach the coherent point),
    // then release the arrival flag.
#pragma unroll
    for (int q = 0; q < 6; ++q) {
      __hip_atomic_store(&ws[q * NB + b], S[q],
                         __ATOMIC_RELAXED, __HIP_MEMORY_SCOPE_AGENT);
      __hip_atomic_store(&ws[(6 + q) * NB + b], W[q],
                         __ATOMIC_RELAXED, __HIP_MEMORY_SCOPE_AGENT);
    }
    __hip_atomic_store(&flags[b], MAGIC,
                       __ATOMIC_RELEASE, __HIP_MEMORY_SCOPE_AGENT);
  }

  // ---- finisher: block 0's wave waits for all 64 flags, then reduces ----
  if (b == 0) {
    // Lane l waits on block l's flag; acquire pairs with block l's release.
    while (__hip_atomic_load(&flags[l], __ATOMIC_ACQUIRE,
                             __HIP_MEMORY_SCOPE_AGENT) != MAGIC) {
      __builtin_amdgcn_s_sleep(1);
    }
    float v[12];
#pragma unroll
    for (int q = 0; q < 12; ++q)
      v[q] = __hip_atomic_load(&ws[q * NB + l],
                               __ATOMIC_RELAXED, __HIP_MEMORY_SCOPE_AGENT);
#pragma unroll
    for (int off = 32; off > 0; off >>= 1) {
#pragma unroll
      for (int q = 0; q < 12; ++q) v[q] += __shfl_down(v[q], off, 64);
    }
    if (l == 0) {
      float r = 0.0f;
#pragma unroll
      for (int q = 0; q < 6; ++q) r += v[6 + q] * v[q];   // sum_t w[t]*S[t]
      out[0] = r * INV_4PI;
    }
  }
}

extern "C" void kernel_launch(void* const* d_in, const int* in_sizes, int n_in,
                              void* d_out, int out_size, void* d_ws, size_t ws_size,
                              hipStream_t stream) {
  const float* bytes = (const float*)d_in[0];
  const int* idx = (const int*)d_in[1];
  float* out = (float*)d_out;
  float* ws = (float*)d_ws;

  gauss_fused<<<dim3(NB), dim3(64), 0, stream>>>(bytes, idx, ws, out);
}